// Round 15
// baseline (154.549 us; speedup 1.0000x reference)
//
#include <hip/hip_runtime.h>
#include <hip/hip_bf16.h>

#define B_    512
#define N_    128
#define E_    300
#define EP    320      // component bytes (fp8), padded to 5*64 so K-slices never straddle
#define CE    1200
#define KP1   1280     // 4 * EP -> 20 K-slices of 64
#define H1_   512
#define H2_   256
#define MT    66048    // 512 * 129 rows
#define VP1   50001
#define NTT   (VP1 * 40)      // table 8B units (40 per 320B row)
#define NTW1  (H1_ * 160)     // W1 8B units
#define NTW2  (H2_ * 64)      // W2 8B units (512B rows, 64 units, fp8 permuted)
#define HSCL  64.f            // H1 fp8 storage scale
#define HINV  0.015625f       // 1/64

typedef __attribute__((ext_vector_type(8))) short bf16x8;
typedef __attribute__((ext_vector_type(4))) float f32x4;
typedef __attribute__((ext_vector_type(4))) unsigned short us4;
typedef __attribute__((ext_vector_type(8))) unsigned short us8;
typedef __attribute__((ext_vector_type(2))) long lx2;

static __device__ __forceinline__ unsigned short f2bf(float f) {
  unsigned int u = __float_as_uint(f);
  u += 0x7fffu + ((u >> 16) & 1u);        // RNE
  return (unsigned short)(u >> 16);
}
static __device__ __forceinline__ float bf2f(unsigned short h) {
  return __uint_as_float(((unsigned int)h) << 16);
}
static __device__ __forceinline__ void gl16(const void* g, void* l) {
  __builtin_amdgcn_global_load_lds((const __attribute__((address_space(1))) unsigned int*)g,
                                   (__attribute__((address_space(3))) unsigned int*)l, 16, 0, 0);
}
static __device__ __forceinline__ unsigned long long pk8f8(
    float f0, float f1, float f2, float f3, float f4, float f5, float f6, float f7) {
  int lo = __builtin_amdgcn_cvt_pk_fp8_f32(f0, f1, 0, false);
  lo = __builtin_amdgcn_cvt_pk_fp8_f32(f2, f3, lo, true);
  int hi = __builtin_amdgcn_cvt_pk_fp8_f32(f4, f5, 0, false);
  hi = __builtin_amdgcn_cvt_pk_fp8_f32(f6, f7, hi, true);
  return ((unsigned long long)(unsigned int)hi << 32) | (unsigned int)lo;
}

// 8 floats at component-offset e (elements), 300-tail handled -> packed fp8 u64
static __device__ __forceinline__ unsigned long long pack_unit(const float* __restrict__ comp,
                                                               int e) {
  if (e < 296) {
    float4 a = *reinterpret_cast<const float4*>(comp + e);
    float4 b = *reinterpret_cast<const float4*>(comp + e + 4);
    return pk8f8(a.x, a.y, a.z, a.w, b.x, b.y, b.z, b.w);
  } else if (e == 296) {
    float4 a = *reinterpret_cast<const float4*>(comp + 296);
    return pk8f8(a.x, a.y, a.z, a.w, 0.f, 0.f, 0.f, 0.f);
  }
  return 0ULL;   // e >= 300 (pad)
}

// ---------------------------------------------------------------- converts
// table/W1/W2 -> fp8 with per-64B-slice 8B-unit permutation: phys p = fg*2+q <- orig q*4+fg
// (a lane's q0+q1 operands become 16B-contiguous in LDS -> b128 fragment reads).
__global__ __launch_bounds__(256) void convert_k(
    const float* __restrict__ table, const float* __restrict__ W1, const float* __restrict__ W2,
    unsigned char* __restrict__ tb8, unsigned char* __restrict__ W1f8,
    unsigned char* __restrict__ W2f8) {
  int i = blockIdx.x * 256 + threadIdx.x;
  if (i < NTT) {
    int r = i / 40, j = i - r * 40;
    int s = j >> 3, p = j & 7;
    int e = s * 64 + ((p & 1) * 4 + (p >> 1)) * 8;     // orig elem offset in component
    unsigned long long o = pack_unit(table + (size_t)r * 300, e);
    *reinterpret_cast<unsigned long long*>(tb8 + (size_t)r * EP + j * 8) = o;
  } else if (i < NTT + NTW1) {
    int j = i - NTT;
    int r = j / 160, jj = j - r * 160;
    int t = jj >> 3, p = jj & 7;
    int k = t * 64 + ((p & 1) * 4 + (p >> 1)) * 8;     // orig offset in padded concat row
    int c = k / EP, e = k - c * EP;
    unsigned long long o = pack_unit(W1 + (size_t)r * CE + c * 300, e);
    *reinterpret_cast<unsigned long long*>(W1f8 + (size_t)r * KP1 + jj * 8) = o;
  } else if (i < NTT + NTW1 + NTW2) {
    int j = i - NTT - NTW1;           // unit over 256 rows x 64 units
    int r = j >> 6, jj = j & 63;
    int s = jj >> 3, p = jj & 7;
    int e = s * 64 + ((p & 1) * 4 + (p >> 1)) * 8;
    const float* src = W2 + (size_t)r * H1_ + e;
    float4 a = *reinterpret_cast<const float4*>(src);
    float4 b = *reinterpret_cast<const float4*>(src + 4);
    unsigned long long o = pk8f8(a.x, a.y, a.z, a.w, b.x, b.y, b.z, b.w);
    *reinterpret_cast<unsigned long long*>(W2f8 + (size_t)r * H1_ + jj * 8) = o;
  }
}

// ---------------------------------------------------------------- GEMM1 (fp8): gather + X@W1^T, relu
// tile 128M x 128N, BK=64 fp8 (20 steps), 256 threads = 4 waves (2x2), wave 64x64.
// 2-phase double-buffer; 32 KB LDS. __launch_bounds__(256,4) caps unified regs at 128
// (64 AGPR acc + <=64 arch VGPR) -> 4 waves/SIMD -> ~4 blocks/CU of cross-block cover.
__global__ __launch_bounds__(256, 4) void gemm1_k(
    const unsigned char* __restrict__ tb8, const unsigned char* __restrict__ W1f8,
    const float* __restrict__ b1, const int* __restrict__ bev, const int* __restrict__ bctx,
    unsigned char* __restrict__ H1f8) {
  __shared__ unsigned char As[2][128 * 64];   // 8 KB each
  __shared__ unsigned char Bs[2][128 * 64];   // 8 KB each -> 32 KB total

  const int tid  = threadIdx.x;
  const int lane = tid & 63;
  const int w    = tid >> 6;
  const int wr   = w >> 1, wc = w & 1;
  const int wgid = (blockIdx.x & 7) * 258 + (blockIdx.x >> 3);   // chunked XCD swizzle (2064=8*258)
  const int m0 = (wgid >> 2) * 128;
  const int n0 = (wgid & 3) * 128;
  const int fr = lane & 15, fg = lane >> 4;

  const int l16 = (tid & 3) ^ ((tid >> 3) & 3);
  int idx[2][4];
#pragma unroll
  for (int i = 0; i < 2; ++i) {
    int mrow = m0 + i * 64 + (tid >> 2);
    int bidx = mrow / 129, nidx = mrow - bidx * 129;
    const int* p = (nidx < 128) ? bctx + ((size_t)bidx * 128 + nidx) * 4
                                : bev + (size_t)bidx * 4;
#pragma unroll
    for (int c = 0; c < 4; ++c) idx[i][c] = p[c];
  }
  const unsigned char* bsrc0 = W1f8 + (size_t)(n0 + (tid >> 2)) * KP1 + l16 * 16;
  const unsigned char* bsrc1 = bsrc0 + (size_t)64 * KP1;
  const int p16f = fg ^ ((fr >> 1) & 3);     // zero-conflict fragment-read slot

  f32x4 acc[4][4];
#pragma unroll
  for (int mi = 0; mi < 4; ++mi)
#pragma unroll
    for (int ni = 0; ni < 4; ++ni)
#pragma unroll
      for (int r = 0; r < 4; ++r) acc[mi][ni][r] = 0.f;

#define STAGE1(BUF, KT)                                                       \
  do {                                                                        \
    int c_ = (KT) / 5;                                                        \
    int e_ = ((KT) - c_ * 5) * 64 + l16 * 16;                                 \
    int id0 = (c_ == 0) ? idx[0][0] : (c_ == 1) ? idx[0][1]                   \
            : (c_ == 2) ? idx[0][2] : idx[0][3];                              \
    int id1 = (c_ == 0) ? idx[1][0] : (c_ == 1) ? idx[1][1]                   \
            : (c_ == 2) ? idx[1][2] : idx[1][3];                              \
    gl16(tb8 + (size_t)id0 * EP + e_, &As[BUF][w * 1024]);                    \
    gl16(tb8 + (size_t)id1 * EP + e_, &As[BUF][4096 + w * 1024]);             \
    gl16(bsrc0 + (size_t)(KT) * 64, &Bs[BUF][w * 1024]);                      \
    gl16(bsrc1 + (size_t)(KT) * 64, &Bs[BUF][4096 + w * 1024]);               \
  } while (0)

#define COMPUTE1(BUF)                                                         \
  do {                                                                        \
    lx2 af[4], bf[4];                                                         \
    _Pragma("unroll")                                                         \
    for (int mi = 0; mi < 4; ++mi)                                            \
      af[mi] = *reinterpret_cast<const lx2*>(                                 \
          &As[BUF][(wr * 64 + mi * 16 + fr) * 64 + p16f * 16]);               \
    _Pragma("unroll")                                                         \
    for (int ni = 0; ni < 4; ++ni)                                            \
      bf[ni] = *reinterpret_cast<const lx2*>(                                 \
          &Bs[BUF][(wc * 64 + ni * 16 + fr) * 64 + p16f * 16]);               \
    __builtin_amdgcn_s_setprio(1);                                            \
    _Pragma("unroll")                                                         \
    for (int mi = 0; mi < 4; ++mi)                                            \
      _Pragma("unroll")                                                       \
      for (int ni = 0; ni < 4; ++ni)                                          \
        acc[mi][ni] = __builtin_amdgcn_mfma_f32_16x16x32_fp8_fp8(             \
            af[mi][0], bf[ni][0], acc[mi][ni], 0, 0, 0);                      \
    _Pragma("unroll")                                                         \
    for (int mi = 0; mi < 4; ++mi)                                            \
      _Pragma("unroll")                                                       \
      for (int ni = 0; ni < 4; ++ni)                                          \
        acc[mi][ni] = __builtin_amdgcn_mfma_f32_16x16x32_fp8_fp8(             \
            af[mi][1], bf[ni][1], acc[mi][ni], 0, 0, 0);                      \
    __builtin_amdgcn_s_setprio(0);                                            \
  } while (0)

  STAGE1(0, 0);
  asm volatile("s_waitcnt vmcnt(0)" ::: "memory");
  __builtin_amdgcn_s_barrier();
  int cur = 0;
  for (int t = 0; t < 20; ++t) {
    if (t < 19) STAGE1(cur ^ 1, t + 1);       // next tile in flight under compute(t)
    COMPUTE1(cur);
    asm volatile("s_waitcnt vmcnt(0)" ::: "memory");   // next tile landed
    __builtin_amdgcn_s_barrier();             // all waves: tile t reads done, t+1 ready
    cur ^= 1;
  }
#undef STAGE1
#undef COMPUTE1

  float bb[4];
  int pos[4];
  const int sbase = (n0 >> 6) + wc;          // 64B-slice index of this wave's columns
#pragma unroll
  for (int ni = 0; ni < 4; ++ni) {
    bb[ni] = b1[n0 + wc * 64 + ni * 16 + fr];
    int u = ni * 16 + fr;                    // within-slice byte (orig)
    pos[ni] = sbase * 64 + (((u >> 3) & 3) * 2 + (u >> 5)) * 8 + (u & 7);
  }
#pragma unroll
  for (int mi = 0; mi < 4; ++mi)
#pragma unroll
    for (int ni = 0; ni < 4; ++ni)
#pragma unroll
      for (int r = 0; r < 4; ++r) {
        float v = fmaxf(acc[mi][ni][r] + bb[ni], 0.f) * HSCL;
        unsigned int pk = __builtin_amdgcn_cvt_pk_fp8_f32(v, v, 0, false);
        int row = m0 + wr * 64 + mi * 16 + fg * 4 + r;
        H1f8[(size_t)row * H1_ + pos[ni]] = (unsigned char)(pk & 0xFF);
      }
}

// ---------------------------------------------------------------- GEMM2 (fp8): H1@W2^T, relu + l2norm
// tile 128M x 256N (full H2 -> norm block-local), BK=64 fp8 (8 steps), 512 threads = 8 waves (2x4).
// 2-phase double-buffer, 48 KB LDS. __launch_bounds__(512,4) -> 128-reg cap, 2 blocks/CU.
__global__ __launch_bounds__(512, 4) void gemm2_k(
    const unsigned char* __restrict__ H1f8, const unsigned char* __restrict__ W2f8,
    const float* __restrict__ b2, unsigned short* __restrict__ RPR) {
  __shared__ unsigned char As[2][128 * 64];   //  8 KB each
  __shared__ unsigned char Bs[2][256 * 64];   // 16 KB each -> 48 KB
  __shared__ float rpart[128][4];
  __shared__ float rinv[128];

  const int tid  = threadIdx.x;
  const int lane = tid & 63;
  const int w    = tid >> 6;
  const int wr   = w >> 2, wc = w & 3;
  const int m0   = blockIdx.x * 128;
  const int fr = lane & 15, fg = lane >> 4;

  const int l16 = (tid & 3) ^ ((tid >> 3) & 3);
  const unsigned char* asrc = H1f8 + (size_t)(m0 + (tid >> 2)) * H1_ + l16 * 16;
  const unsigned char* bsrc = W2f8 + (size_t)(tid >> 2) * H1_ + l16 * 16;
  const int p16f = fg ^ ((fr >> 1) & 3);

  f32x4 acc[4][4];
#pragma unroll
  for (int mi = 0; mi < 4; ++mi)
#pragma unroll
    for (int ni = 0; ni < 4; ++ni)
#pragma unroll
      for (int r = 0; r < 4; ++r) acc[mi][ni][r] = 0.f;

#define STAGE2(BUF, KT)                                                       \
  do {                                                                        \
    gl16(asrc + (KT) * 64, &As[BUF][w * 1024]);                               \
    gl16(bsrc + (KT) * 64, &Bs[BUF][w * 1024]);                               \
    gl16(bsrc + (size_t)128 * H1_ + (KT) * 64, &Bs[BUF][8192 + w * 1024]);    \
  } while (0)

#define COMPUTE2(BUF)                                                         \
  do {                                                                        \
    lx2 af[4], bf[4];                                                         \
    _Pragma("unroll")                                                         \
    for (int mi = 0; mi < 4; ++mi)                                            \
      af[mi] = *reinterpret_cast<const lx2*>(                                 \
          &As[BUF][(wr * 64 + mi * 16 + fr) * 64 + p16f * 16]);               \
    _Pragma("unroll")                                                         \
    for (int ni = 0; ni < 4; ++ni)                                            \
      bf[ni] = *reinterpret_cast<const lx2*>(                                 \
          &Bs[BUF][(wc * 64 + ni * 16 + fr) * 64 + p16f * 16]);               \
    __builtin_amdgcn_s_setprio(1);                                            \
    _Pragma("unroll")                                                         \
    for (int mi = 0; mi < 4; ++mi)                                            \
      _Pragma("unroll")                                                       \
      for (int ni = 0; ni < 4; ++ni)                                          \
        acc[mi][ni] = __builtin_amdgcn_mfma_f32_16x16x32_fp8_fp8(             \
            af[mi][0], bf[ni][0], acc[mi][ni], 0, 0, 0);                      \
    _Pragma("unroll")                                                         \
    for (int mi = 0; mi < 4; ++mi)                                            \
      _Pragma("unroll")                                                       \
      for (int ni = 0; ni < 4; ++ni)                                          \
        acc[mi][ni] = __builtin_amdgcn_mfma_f32_16x16x32_fp8_fp8(             \
            af[mi][1], bf[ni][1], acc[mi][ni], 0, 0, 0);                      \
    __builtin_amdgcn_s_setprio(0);                                            \
  } while (0)

  STAGE2(0, 0);
  asm volatile("s_waitcnt vmcnt(0)" ::: "memory");
  __builtin_amdgcn_s_barrier();
  int cur = 0;
  for (int t = 0; t < 8; ++t) {
    if (t < 7) STAGE2(cur ^ 1, t + 1);
    COMPUTE2(cur);
    asm volatile("s_waitcnt vmcnt(0)" ::: "memory");
    __builtin_amdgcn_s_barrier();
    cur ^= 1;
  }
#undef STAGE2
#undef COMPUTE2

  float bb[4];
#pragma unroll
  for (int ni = 0; ni < 4; ++ni) bb[ni] = b2[wc * 64 + ni * 16 + fr];
#pragma unroll
  for (int mi = 0; mi < 4; ++mi)
#pragma unroll
    for (int ni = 0; ni < 4; ++ni)
#pragma unroll
      for (int r = 0; r < 4; ++r)
        acc[mi][ni][r] = fmaxf(acc[mi][ni][r] * HINV + bb[ni], 0.f);

#pragma unroll
  for (int mi = 0; mi < 4; ++mi)
#pragma unroll
    for (int r = 0; r < 4; ++r) {
      float s = 0.f;
#pragma unroll
      for (int ni = 0; ni < 4; ++ni) s += acc[mi][ni][r] * acc[mi][ni][r];
      s += __shfl_xor(s, 1); s += __shfl_xor(s, 2);
      s += __shfl_xor(s, 4); s += __shfl_xor(s, 8);
      if (fr == 0) rpart[wr * 64 + mi * 16 + fg * 4 + r][wc] = s;
    }
  __syncthreads();
  if (tid < 128) {
    float s = rpart[tid][0] + rpart[tid][1] + rpart[tid][2] + rpart[tid][3];
    rinv[tid] = 1.f / fmaxf(sqrtf(s), 1e-12f);
  }
  __syncthreads();

#pragma unroll
  for (int mi = 0; mi < 4; ++mi)
#pragma unroll
    for (int r = 0; r < 4; ++r) {
      int lrow = wr * 64 + mi * 16 + fg * 4 + r;
      float sc = rinv[lrow];
#pragma unroll
      for (int ni = 0; ni < 4; ++ni) {
        int col = wc * 64 + ni * 16 + fr;
        RPR[(size_t)(m0 + lrow) * H2_ + col] = f2bf(acc[mi][ni][r] * sc);
      }
    }
}

// ---------------------------------------------------------------- final: dots (RPR pre-normalized),
// variances, KNRM, score, sigmoid. 256 threads = 4 waves per batch.
__global__ __launch_bounds__(256) void final_k(
    const float* __restrict__ table, const float* __restrict__ Wv, const float* __restrict__ bv,
    const float* __restrict__ Wc, const float* __restrict__ bc, const int* __restrict__ bev,
    const float* __restrict__ bdist, const float* __restrict__ bfeat,
    const unsigned short* __restrict__ RPR, float* __restrict__ out) {
  const int b = blockIdx.x, tid = threadIdx.x, lane = tid & 63, w = tid >> 6;
  __shared__ float pred[E_];
  __shared__ float tarr[128];
  __shared__ float var_s[9];
  __shared__ float pool_s[2][11];

  const float MU[11]  = {1.0f, 0.9f, 0.7f, 0.5f, 0.3f, 0.1f, -0.1f, -0.3f, -0.5f, -0.7f, -0.9f};
  const float IS2[11] = {500000.f, 50.f, 50.f, 50.f, 50.f, 50.f, 50.f, 50.f, 50.f, 50.f, 50.f};

  const int prow = bev[b * 4 + 1];
  for (int e = tid; e < E_; e += 256) pred[e] = table[(size_t)prow * E_ + e];
  __syncthreads();

  if (tid < 144) {
    int j = tid >> 4, l = tid & 15;
    float s = 0.f;
    for (int e = l; e < E_; e += 16) s += pred[e] * Wv[j * E_ + e];
    s += __shfl_xor(s, 1); s += __shfl_xor(s, 2);
    s += __shfl_xor(s, 4); s += __shfl_xor(s, 8);
    if (l == 0) {
      float x = s + bv[j];
      var_s[j] = fmaxf(x, 0.f) + log1pf(expf(-fabsf(x)));   // softplus
    }
  }

  const unsigned short* evp = RPR + ((size_t)b * 129 + 128) * H2_;
  us4 e4 = *reinterpret_cast<const us4*>(evp + lane * 4);
  const float e0 = bf2f(e4[0]), e1 = bf2f(e4[1]), e2 = bf2f(e4[2]), e3 = bf2f(e4[3]);
  for (int k = 0; k < 32; ++k) {
    int n = w * 32 + k;
    const unsigned short* cp = RPR + ((size_t)b * 129 + n) * H2_;
    us4 c4 = *reinterpret_cast<const us4*>(cp + lane * 4);
    float d = e0 * bf2f(c4[0]) + e1 * bf2f(c4[1]) + e2 * bf2f(c4[2]) + e3 * bf2f(c4[3]);
#pragma unroll
    for (int off = 32; off; off >>= 1) d += __shfl_xor(d, off);
    if (lane == 0) tarr[n] = d;
  }
  __syncthreads();

  if (tid < 128) {
    float t = tarr[tid];
    float kv[11];
#pragma unroll
    for (int kk = 0; kk < 11; ++kk) {
      float u = t - MU[kk];
      kv[kk] = expf(-u * u * IS2[kk]);
    }
#pragma unroll
    for (int off = 32; off; off >>= 1)
#pragma unroll
      for (int kk = 0; kk < 11; ++kk) kv[kk] += __shfl_xor(kv[kk], off);
    if (lane == 0)
#pragma unroll
      for (int kk = 0; kk < 11; ++kk) pool_s[w][kk] = kv[kk];
  }
  __syncthreads();

  if (tid == 0) {
    float score = bc[0];
    for (int j = 0; j < 9; ++j) {
      float d = bdist[b * 9 + j];
      score += Wc[j] * expf(-(d * d) / var_s[j]);
    }
    for (int i = 0; i < 8; ++i) score += Wc[9 + i] * bfeat[b * 8 + i];
    for (int kk = 0; kk < 11; ++kk) {
      float p = fmaxf(pool_s[0][kk] + pool_s[1][kk], 1e-10f);
      score += Wc[17 + kk] * (0.01f * logf(p));
    }
    out[b] = 1.f / (1.f + expf(-score));
  }
}

// ----------------------------------------------------------------
extern "C" void kernel_launch(void* const* d_in, const int* in_sizes, int n_in,
                              void* d_out, int out_size, void* d_ws, size_t ws_size,
                              hipStream_t stream) {
  const float* table = (const float*)d_in[0];
  const float* W1    = (const float*)d_in[1];
  const float* b1    = (const float*)d_in[2];
  const float* W2    = (const float*)d_in[3];
  const float* b2    = (const float*)d_in[4];
  const float* Wv    = (const float*)d_in[5];
  const float* bv    = (const float*)d_in[6];
  const float* Wc    = (const float*)d_in[7];
  const float* bc    = (const float*)d_in[8];
  const int*   bev   = (const int*)d_in[9];
  const float* bfeat = (const float*)d_in[10];
  const float* bdist = (const float*)d_in[11];
  const int*   bctx  = (const int*)d_in[12];
  float* out = (float*)d_out;

  auto align64 = [](size_t x) { return (x + 63) & ~(size_t)63; };
  size_t off = 0;
  size_t o_tb8  = off; off += align64((size_t)VP1 * EP);            // 16.0 MB fp8 table
  size_t o_W1f8 = off; off += align64((size_t)H1_ * KP1);           //  0.66 MB fp8 W1
  size_t o_W2f8 = off; off += align64((size_t)H2_ * H1_);           //  0.13 MB fp8 W2
  size_t o_H1   = off; off += align64((size_t)MT * H1_);            // 33.8 MB fp8 H1
  size_t o_RPR  = off; off += align64((size_t)MT * H2_ * 2);        // 33.8 MB bf16 RPR
  if (ws_size < off) {                       // loud, distinguishable failure
    hipMemsetAsync(d_out, 0xBF, (size_t)out_size * 4, stream);
    return;
  }
  char* ws = (char*)d_ws;
  unsigned char*  tb8   = (unsigned char*)(ws + o_tb8);
  unsigned char*  W1f8  = (unsigned char*)(ws + o_W1f8);
  unsigned char*  W2f8  = (unsigned char*)(ws + o_W2f8);
  unsigned char*  H1f8  = (unsigned char*)(ws + o_H1);
  unsigned short* RPR   = (unsigned short*)(ws + o_RPR);

  const int conv_items = NTT + NTW1 + NTW2;
  hipLaunchKernelGGL(convert_k, dim3((conv_items + 255) / 256), dim3(256), 0, stream,
                     table, W1, W2, tb8, W1f8, W2f8);
  hipLaunchKernelGGL(gemm1_k, dim3(MT / 128 * 4), dim3(256), 0, stream,
                     tb8, W1f8, b1, bev, bctx, H1f8);
  hipLaunchKernelGGL(gemm2_k, dim3(MT / 128), dim3(512), 0, stream, H1f8, W2f8, b2, RPR);
  hipLaunchKernelGGL(final_k, dim3(B_), dim3(256), 0, stream,
                     table, Wv, bv, Wc, bc, bev, bdist, bfeat, RPR, out);
}

// Round 16
// 145.926 us; speedup vs baseline: 1.0591x; 1.0591x over previous
//
#include <hip/hip_runtime.h>
#include <hip/hip_bf16.h>

#define B_    512
#define N_    128
#define E_    300
#define EP    320      // component bytes (fp8), padded to 5*64 so K-slices never straddle
#define CE    1200
#define KP1   1280     // 4 * EP -> 20 K-slices of 64
#define H1_   512
#define H2_   256
#define MT    66048    // 512 * 129 rows
#define VP1   50001
#define NTT   (VP1 * 40)      // table 8B units (40 per 320B row)
#define NTW1  (H1_ * 160)     // W1 8B units
#define NTW2  (H2_ * 64)      // W2 8B units (512B rows, 64 units, fp8 permuted)
#define HSCL  64.f            // H1 fp8 storage scale
#define HINV  0.015625f       // 1/64

typedef __attribute__((ext_vector_type(8))) short bf16x8;
typedef __attribute__((ext_vector_type(4))) float f32x4;
typedef __attribute__((ext_vector_type(4))) unsigned short us4;
typedef __attribute__((ext_vector_type(8))) unsigned short us8;
typedef __attribute__((ext_vector_type(2))) long lx2;

static __device__ __forceinline__ unsigned short f2bf(float f) {
  unsigned int u = __float_as_uint(f);
  u += 0x7fffu + ((u >> 16) & 1u);        // RNE
  return (unsigned short)(u >> 16);
}
static __device__ __forceinline__ float bf2f(unsigned short h) {
  return __uint_as_float(((unsigned int)h) << 16);
}
static __device__ __forceinline__ void gl16(const void* g, void* l) {
  __builtin_amdgcn_global_load_lds((const __attribute__((address_space(1))) unsigned int*)g,
                                   (__attribute__((address_space(3))) unsigned int*)l, 16, 0, 0);
}
static __device__ __forceinline__ unsigned long long pk8f8(
    float f0, float f1, float f2, float f3, float f4, float f5, float f6, float f7) {
  int lo = __builtin_amdgcn_cvt_pk_fp8_f32(f0, f1, 0, false);
  lo = __builtin_amdgcn_cvt_pk_fp8_f32(f2, f3, lo, true);
  int hi = __builtin_amdgcn_cvt_pk_fp8_f32(f4, f5, 0, false);
  hi = __builtin_amdgcn_cvt_pk_fp8_f32(f6, f7, hi, true);
  return ((unsigned long long)(unsigned int)hi << 32) | (unsigned int)lo;
}

// 8 floats at component-offset e (elements), 300-tail handled -> packed fp8 u64
static __device__ __forceinline__ unsigned long long pack_unit(const float* __restrict__ comp,
                                                               int e) {
  if (e < 296) {
    float4 a = *reinterpret_cast<const float4*>(comp + e);
    float4 b = *reinterpret_cast<const float4*>(comp + e + 4);
    return pk8f8(a.x, a.y, a.z, a.w, b.x, b.y, b.z, b.w);
  } else if (e == 296) {
    float4 a = *reinterpret_cast<const float4*>(comp + 296);
    return pk8f8(a.x, a.y, a.z, a.w, 0.f, 0.f, 0.f, 0.f);
  }
  return 0ULL;   // e >= 300 (pad)
}

// ---------------------------------------------------------------- converts
// table/W1/W2 -> fp8 with per-64B-slice 8B-unit permutation: phys p = fg*2+q <- orig q*4+fg
// (a lane's q0+q1 operands become 16B-contiguous in LDS -> b128 fragment reads).
__global__ __launch_bounds__(256) void convert_k(
    const float* __restrict__ table, const float* __restrict__ W1, const float* __restrict__ W2,
    unsigned char* __restrict__ tb8, unsigned char* __restrict__ W1f8,
    unsigned char* __restrict__ W2f8) {
  int i = blockIdx.x * 256 + threadIdx.x;
  if (i < NTT) {
    int r = i / 40, j = i - r * 40;
    int s = j >> 3, p = j & 7;
    int e = s * 64 + ((p & 1) * 4 + (p >> 1)) * 8;     // orig elem offset in component
    unsigned long long o = pack_unit(table + (size_t)r * 300, e);
    *reinterpret_cast<unsigned long long*>(tb8 + (size_t)r * EP + j * 8) = o;
  } else if (i < NTT + NTW1) {
    int j = i - NTT;
    int r = j / 160, jj = j - r * 160;
    int t = jj >> 3, p = jj & 7;
    int k = t * 64 + ((p & 1) * 4 + (p >> 1)) * 8;     // orig offset in padded concat row
    int c = k / EP, e = k - c * EP;
    unsigned long long o = pack_unit(W1 + (size_t)r * CE + c * 300, e);
    *reinterpret_cast<unsigned long long*>(W1f8 + (size_t)r * KP1 + jj * 8) = o;
  } else if (i < NTT + NTW1 + NTW2) {
    int j = i - NTT - NTW1;           // unit over 256 rows x 64 units
    int r = j >> 6, jj = j & 63;
    int s = jj >> 3, p = jj & 7;
    int e = s * 64 + ((p & 1) * 4 + (p >> 1)) * 8;
    const float* src = W2 + (size_t)r * H1_ + e;
    float4 a = *reinterpret_cast<const float4*>(src);
    float4 b = *reinterpret_cast<const float4*>(src + 4);
    unsigned long long o = pk8f8(a.x, a.y, a.z, a.w, b.x, b.y, b.z, b.w);
    *reinterpret_cast<unsigned long long*>(W2f8 + (size_t)r * H1_ + jj * 8) = o;
  }
}

// ---------------------------------------------------------------- GEMM1 (fp8): gather + X@W1^T, relu
// tile 128M x 128N, BK=64 fp8 (20 steps), 256 threads = 4 waves (2x2), wave 64x64.
// 2-phase double-buffer (T3-minimum): STAGE(t+1) | COMPUTE(t) | vmcnt(0) | barrier.
// 32 KB LDS. No launch_bounds reg cap: 144 unified regs live (80 arch + 64 acc) beats
// spills at higher occupancy (R15 measured: cap -> +29 MB scratch writes, -14% perf).
__global__ __launch_bounds__(256) void gemm1_k(
    const unsigned char* __restrict__ tb8, const unsigned char* __restrict__ W1f8,
    const float* __restrict__ b1, const int* __restrict__ bev, const int* __restrict__ bctx,
    unsigned char* __restrict__ H1f8) {
  __shared__ unsigned char As[2][128 * 64];   // 8 KB each
  __shared__ unsigned char Bs[2][128 * 64];   // 8 KB each -> 32 KB total

  const int tid  = threadIdx.x;
  const int lane = tid & 63;
  const int w    = tid >> 6;
  const int wr   = w >> 1, wc = w & 1;
  const int wgid = (blockIdx.x & 7) * 258 + (blockIdx.x >> 3);   // chunked XCD swizzle (2064=8*258)
  const int m0 = (wgid >> 2) * 128;
  const int n0 = (wgid & 3) * 128;
  const int fr = lane & 15, fg = lane >> 4;

  const int l16 = (tid & 3) ^ ((tid >> 3) & 3);
  int idx[2][4];
#pragma unroll
  for (int i = 0; i < 2; ++i) {
    int mrow = m0 + i * 64 + (tid >> 2);
    int bidx = mrow / 129, nidx = mrow - bidx * 129;
    const int* p = (nidx < 128) ? bctx + ((size_t)bidx * 128 + nidx) * 4
                                : bev + (size_t)bidx * 4;
#pragma unroll
    for (int c = 0; c < 4; ++c) idx[i][c] = p[c];
  }
  const unsigned char* bsrc0 = W1f8 + (size_t)(n0 + (tid >> 2)) * KP1 + l16 * 16;
  const unsigned char* bsrc1 = bsrc0 + (size_t)64 * KP1;
  const int p16f = fg ^ ((fr >> 1) & 3);     // zero-conflict fragment-read slot

  f32x4 acc[4][4];
#pragma unroll
  for (int mi = 0; mi < 4; ++mi)
#pragma unroll
    for (int ni = 0; ni < 4; ++ni)
#pragma unroll
      for (int r = 0; r < 4; ++r) acc[mi][ni][r] = 0.f;

#define STAGE1(BUF, KT)                                                       \
  do {                                                                        \
    int c_ = (KT) / 5;                                                        \
    int e_ = ((KT) - c_ * 5) * 64 + l16 * 16;                                 \
    int id0 = (c_ == 0) ? idx[0][0] : (c_ == 1) ? idx[0][1]                   \
            : (c_ == 2) ? idx[0][2] : idx[0][3];                              \
    int id1 = (c_ == 0) ? idx[1][0] : (c_ == 1) ? idx[1][1]                   \
            : (c_ == 2) ? idx[1][2] : idx[1][3];                              \
    gl16(tb8 + (size_t)id0 * EP + e_, &As[BUF][w * 1024]);                    \
    gl16(tb8 + (size_t)id1 * EP + e_, &As[BUF][4096 + w * 1024]);             \
    gl16(bsrc0 + (size_t)(KT) * 64, &Bs[BUF][w * 1024]);                      \
    gl16(bsrc1 + (size_t)(KT) * 64, &Bs[BUF][4096 + w * 1024]);               \
  } while (0)

#define COMPUTE1(BUF)                                                         \
  do {                                                                        \
    lx2 af[4], bf[4];                                                         \
    _Pragma("unroll")                                                         \
    for (int mi = 0; mi < 4; ++mi)                                            \
      af[mi] = *reinterpret_cast<const lx2*>(                                 \
          &As[BUF][(wr * 64 + mi * 16 + fr) * 64 + p16f * 16]);               \
    _Pragma("unroll")                                                         \
    for (int ni = 0; ni < 4; ++ni)                                            \
      bf[ni] = *reinterpret_cast<const lx2*>(                                 \
          &Bs[BUF][(wc * 64 + ni * 16 + fr) * 64 + p16f * 16]);               \
    __builtin_amdgcn_s_setprio(1);                                            \
    _Pragma("unroll")                                                         \
    for (int mi = 0; mi < 4; ++mi)                                            \
      _Pragma("unroll")                                                       \
      for (int ni = 0; ni < 4; ++ni)                                          \
        acc[mi][ni] = __builtin_amdgcn_mfma_f32_16x16x32_fp8_fp8(             \
            af[mi][0], bf[ni][0], acc[mi][ni], 0, 0, 0);                      \
    _Pragma("unroll")                                                         \
    for (int mi = 0; mi < 4; ++mi)                                            \
      _Pragma("unroll")                                                       \
      for (int ni = 0; ni < 4; ++ni)                                          \
        acc[mi][ni] = __builtin_amdgcn_mfma_f32_16x16x32_fp8_fp8(             \
            af[mi][1], bf[ni][1], acc[mi][ni], 0, 0, 0);                      \
    __builtin_amdgcn_s_setprio(0);                                            \
  } while (0)

  STAGE1(0, 0);
  asm volatile("s_waitcnt vmcnt(0)" ::: "memory");
  __builtin_amdgcn_s_barrier();
  int cur = 0;
  for (int t = 0; t < 20; ++t) {
    if (t < 19) STAGE1(cur ^ 1, t + 1);       // next tile in flight under compute(t)
    COMPUTE1(cur);
    asm volatile("s_waitcnt vmcnt(0)" ::: "memory");   // next tile landed
    __builtin_amdgcn_s_barrier();             // all waves: tile t reads done, t+1 ready
    cur ^= 1;
  }
#undef STAGE1
#undef COMPUTE1

  float bb[4];
  int pos[4];
  const int sbase = (n0 >> 6) + wc;          // 64B-slice index of this wave's columns
#pragma unroll
  for (int ni = 0; ni < 4; ++ni) {
    bb[ni] = b1[n0 + wc * 64 + ni * 16 + fr];
    int u = ni * 16 + fr;                    // within-slice byte (orig)
    pos[ni] = sbase * 64 + (((u >> 3) & 3) * 2 + (u >> 5)) * 8 + (u & 7);
  }
#pragma unroll
  for (int mi = 0; mi < 4; ++mi)
#pragma unroll
    for (int ni = 0; ni < 4; ++ni)
#pragma unroll
      for (int r = 0; r < 4; ++r) {
        float v = fmaxf(acc[mi][ni][r] + bb[ni], 0.f) * HSCL;
        unsigned int pk = __builtin_amdgcn_cvt_pk_fp8_f32(v, v, 0, false);
        int row = m0 + wr * 64 + mi * 16 + fg * 4 + r;
        H1f8[(size_t)row * H1_ + pos[ni]] = (unsigned char)(pk & 0xFF);
      }
}

// ---------------------------------------------------------------- GEMM2 (fp8): H1@W2^T, relu + l2norm
// tile 128M x 256N (full H2 -> norm block-local), BK=64 fp8 (8 steps), 512 threads = 8 waves (2x4).
// 2-phase double-buffer, 48 KB LDS. De-scale 1/64 folded pre-bias.
__global__ __launch_bounds__(512) void gemm2_k(
    const unsigned char* __restrict__ H1f8, const unsigned char* __restrict__ W2f8,
    const float* __restrict__ b2, unsigned short* __restrict__ RPR) {
  __shared__ unsigned char As[2][128 * 64];   //  8 KB each
  __shared__ unsigned char Bs[2][256 * 64];   // 16 KB each -> 48 KB
  __shared__ float rpart[128][4];
  __shared__ float rinv[128];

  const int tid  = threadIdx.x;
  const int lane = tid & 63;
  const int w    = tid >> 6;
  const int wr   = w >> 2, wc = w & 3;
  const int m0   = blockIdx.x * 128;
  const int fr = lane & 15, fg = lane >> 4;

  const int l16 = (tid & 3) ^ ((tid >> 3) & 3);
  const unsigned char* asrc = H1f8 + (size_t)(m0 + (tid >> 2)) * H1_ + l16 * 16;
  const unsigned char* bsrc = W2f8 + (size_t)(tid >> 2) * H1_ + l16 * 16;
  const int p16f = fg ^ ((fr >> 1) & 3);

  f32x4 acc[4][4];
#pragma unroll
  for (int mi = 0; mi < 4; ++mi)
#pragma unroll
    for (int ni = 0; ni < 4; ++ni)
#pragma unroll
      for (int r = 0; r < 4; ++r) acc[mi][ni][r] = 0.f;

#define STAGE2(BUF, KT)                                                       \
  do {                                                                        \
    gl16(asrc + (KT) * 64, &As[BUF][w * 1024]);                               \
    gl16(bsrc + (KT) * 64, &Bs[BUF][w * 1024]);                               \
    gl16(bsrc + (size_t)128 * H1_ + (KT) * 64, &Bs[BUF][8192 + w * 1024]);    \
  } while (0)

#define COMPUTE2(BUF)                                                         \
  do {                                                                        \
    lx2 af[4], bf[4];                                                         \
    _Pragma("unroll")                                                         \
    for (int mi = 0; mi < 4; ++mi)                                            \
      af[mi] = *reinterpret_cast<const lx2*>(                                 \
          &As[BUF][(wr * 64 + mi * 16 + fr) * 64 + p16f * 16]);               \
    _Pragma("unroll")                                                         \
    for (int ni = 0; ni < 4; ++ni)                                            \
      bf[ni] = *reinterpret_cast<const lx2*>(                                 \
          &Bs[BUF][(wc * 64 + ni * 16 + fr) * 64 + p16f * 16]);               \
    __builtin_amdgcn_s_setprio(1);                                            \
    _Pragma("unroll")                                                         \
    for (int mi = 0; mi < 4; ++mi)                                            \
      _Pragma("unroll")                                                       \
      for (int ni = 0; ni < 4; ++ni)                                          \
        acc[mi][ni] = __builtin_amdgcn_mfma_f32_16x16x32_fp8_fp8(             \
            af[mi][0], bf[ni][0], acc[mi][ni], 0, 0, 0);                      \
    _Pragma("unroll")                                                         \
    for (int mi = 0; mi < 4; ++mi)                                            \
      _Pragma("unroll")                                                       \
      for (int ni = 0; ni < 4; ++ni)                                          \
        acc[mi][ni] = __builtin_amdgcn_mfma_f32_16x16x32_fp8_fp8(             \
            af[mi][1], bf[ni][1], acc[mi][ni], 0, 0, 0);                      \
    __builtin_amdgcn_s_setprio(0);                                            \
  } while (0)

  STAGE2(0, 0);
  asm volatile("s_waitcnt vmcnt(0)" ::: "memory");
  __builtin_amdgcn_s_barrier();
  int cur = 0;
  for (int t = 0; t < 8; ++t) {
    if (t < 7) STAGE2(cur ^ 1, t + 1);
    COMPUTE2(cur);
    asm volatile("s_waitcnt vmcnt(0)" ::: "memory");
    __builtin_amdgcn_s_barrier();
    cur ^= 1;
  }
#undef STAGE2
#undef COMPUTE2

  float bb[4];
#pragma unroll
  for (int ni = 0; ni < 4; ++ni) bb[ni] = b2[wc * 64 + ni * 16 + fr];
#pragma unroll
  for (int mi = 0; mi < 4; ++mi)
#pragma unroll
    for (int ni = 0; ni < 4; ++ni)
#pragma unroll
      for (int r = 0; r < 4; ++r)
        acc[mi][ni][r] = fmaxf(acc[mi][ni][r] * HINV + bb[ni], 0.f);

#pragma unroll
  for (int mi = 0; mi < 4; ++mi)
#pragma unroll
    for (int r = 0; r < 4; ++r) {
      float s = 0.f;
#pragma unroll
      for (int ni = 0; ni < 4; ++ni) s += acc[mi][ni][r] * acc[mi][ni][r];
      s += __shfl_xor(s, 1); s += __shfl_xor(s, 2);
      s += __shfl_xor(s, 4); s += __shfl_xor(s, 8);
      if (fr == 0) rpart[wr * 64 + mi * 16 + fg * 4 + r][wc] = s;
    }
  __syncthreads();
  if (tid < 128) {
    float s = rpart[tid][0] + rpart[tid][1] + rpart[tid][2] + rpart[tid][3];
    rinv[tid] = 1.f / fmaxf(sqrtf(s), 1e-12f);
  }
  __syncthreads();

#pragma unroll
  for (int mi = 0; mi < 4; ++mi)
#pragma unroll
    for (int r = 0; r < 4; ++r) {
      int lrow = wr * 64 + mi * 16 + fg * 4 + r;
      float sc = rinv[lrow];
#pragma unroll
      for (int ni = 0; ni < 4; ++ni) {
        int col = wc * 64 + ni * 16 + fr;
        RPR[(size_t)(m0 + lrow) * H2_ + col] = f2bf(acc[mi][ni][r] * sc);
      }
    }
}

// ---------------------------------------------------------------- final: dots (RPR pre-normalized),
// variances, KNRM, score, sigmoid. 256 threads = 4 waves per batch.
__global__ __launch_bounds__(256) void final_k(
    const float* __restrict__ table, const float* __restrict__ Wv, const float* __restrict__ bv,
    const float* __restrict__ Wc, const float* __restrict__ bc, const int* __restrict__ bev,
    const float* __restrict__ bdist, const float* __restrict__ bfeat,
    const unsigned short* __restrict__ RPR, float* __restrict__ out) {
  const int b = blockIdx.x, tid = threadIdx.x, lane = tid & 63, w = tid >> 6;
  __shared__ float pred[E_];
  __shared__ float tarr[128];
  __shared__ float var_s[9];
  __shared__ float pool_s[2][11];

  const float MU[11]  = {1.0f, 0.9f, 0.7f, 0.5f, 0.3f, 0.1f, -0.1f, -0.3f, -0.5f, -0.7f, -0.9f};
  const float IS2[11] = {500000.f, 50.f, 50.f, 50.f, 50.f, 50.f, 50.f, 50.f, 50.f, 50.f, 50.f};

  const int prow = bev[b * 4 + 1];
  for (int e = tid; e < E_; e += 256) pred[e] = table[(size_t)prow * E_ + e];
  __syncthreads();

  if (tid < 144) {
    int j = tid >> 4, l = tid & 15;
    float s = 0.f;
    for (int e = l; e < E_; e += 16) s += pred[e] * Wv[j * E_ + e];
    s += __shfl_xor(s, 1); s += __shfl_xor(s, 2);
    s += __shfl_xor(s, 4); s += __shfl_xor(s, 8);
    if (l == 0) {
      float x = s + bv[j];
      var_s[j] = fmaxf(x, 0.f) + log1pf(expf(-fabsf(x)));   // softplus
    }
  }

  const unsigned short* evp = RPR + ((size_t)b * 129 + 128) * H2_;
  us4 e4 = *reinterpret_cast<const us4*>(evp + lane * 4);
  const float e0 = bf2f(e4[0]), e1 = bf2f(e4[1]), e2 = bf2f(e4[2]), e3 = bf2f(e4[3]);
  for (int k = 0; k < 32; ++k) {
    int n = w * 32 + k;
    const unsigned short* cp = RPR + ((size_t)b * 129 + n) * H2_;
    us4 c4 = *reinterpret_cast<const us4*>(cp + lane * 4);
    float d = e0 * bf2f(c4[0]) + e1 * bf2f(c4[1]) + e2 * bf2f(c4[2]) + e3 * bf2f(c4[3]);
#pragma unroll
    for (int off = 32; off; off >>= 1) d += __shfl_xor(d, off);
    if (lane == 0) tarr[n] = d;
  }
  __syncthreads();

  if (tid < 128) {
    float t = tarr[tid];
    float kv[11];
#pragma unroll
    for (int kk = 0; kk < 11; ++kk) {
      float u = t - MU[kk];
      kv[kk] = expf(-u * u * IS2[kk]);
    }
#pragma unroll
    for (int off = 32; off; off >>= 1)
#pragma unroll
      for (int kk = 0; kk < 11; ++kk) kv[kk] += __shfl_xor(kv[kk], off);
    if (lane == 0)
#pragma unroll
      for (int kk = 0; kk < 11; ++kk) pool_s[w][kk] = kv[kk];
  }
  __syncthreads();

  if (tid == 0) {
    float score = bc[0];
    for (int j = 0; j < 9; ++j) {
      float d = bdist[b * 9 + j];
      score += Wc[j] * expf(-(d * d) / var_s[j]);
    }
    for (int i = 0; i < 8; ++i) score += Wc[9 + i] * bfeat[b * 8 + i];
    for (int kk = 0; kk < 11; ++kk) {
      float p = fmaxf(pool_s[0][kk] + pool_s[1][kk], 1e-10f);
      score += Wc[17 + kk] * (0.01f * logf(p));
    }
    out[b] = 1.f / (1.f + expf(-score));
  }
}

// ----------------------------------------------------------------
extern "C" void kernel_launch(void* const* d_in, const int* in_sizes, int n_in,
                              void* d_out, int out_size, void* d_ws, size_t ws_size,
                              hipStream_t stream) {
  const float* table = (const float*)d_in[0];
  const float* W1    = (const float*)d_in[1];
  const float* b1    = (const float*)d_in[2];
  const float* W2    = (const float*)d_in[3];
  const float* b2    = (const float*)d_in[4];
  const float* Wv    = (const float*)d_in[5];
  const float* bv    = (const float*)d_in[6];
  const float* Wc    = (const float*)d_in[7];
  const float* bc    = (const float*)d_in[8];
  const int*   bev   = (const int*)d_in[9];
  const float* bfeat = (const float*)d_in[10];
  const float* bdist = (const float*)d_in[11];
  const int*   bctx  = (const int*)d_in[12];
  float* out = (float*)d_out;

  auto align64 = [](size_t x) { return (x + 63) & ~(size_t)63; };
  size_t off = 0;
  size_t o_tb8  = off; off += align64((size_t)VP1 * EP);            // 16.0 MB fp8 table
  size_t o_W1f8 = off; off += align64((size_t)H1_ * KP1);           //  0.66 MB fp8 W1
  size_t o_W2f8 = off; off += align64((size_t)H2_ * H1_);           //  0.13 MB fp8 W2
  size_t o_H1   = off; off += align64((size_t)MT * H1_);            // 33.8 MB fp8 H1
  size_t o_RPR  = off; off += align64((size_t)MT * H2_ * 2);        // 33.8 MB bf16 RPR
  if (ws_size < off) {                       // loud, distinguishable failure
    hipMemsetAsync(d_out, 0xBF, (size_t)out_size * 4, stream);
    return;
  }
  char* ws = (char*)d_ws;
  unsigned char*  tb8   = (unsigned char*)(ws + o_tb8);
  unsigned char*  W1f8  = (unsigned char*)(ws + o_W1f8);
  unsigned char*  W2f8  = (unsigned char*)(ws + o_W2f8);
  unsigned char*  H1f8  = (unsigned char*)(ws + o_H1);
  unsigned short* RPR   = (unsigned short*)(ws + o_RPR);

  const int conv_items = NTT + NTW1 + NTW2;
  hipLaunchKernelGGL(convert_k, dim3((conv_items + 255) / 256), dim3(256), 0, stream,
                     table, W1, W2, tb8, W1f8, W2f8);
  hipLaunchKernelGGL(gemm1_k, dim3(MT / 128 * 4), dim3(256), 0, stream,
                     tb8, W1f8, b1, bev, bctx, H1f8);
  hipLaunchKernelGGL(gemm2_k, dim3(MT / 128), dim3(512), 0, stream, H1f8, W2f8, b2, RPR);
  hipLaunchKernelGGL(final_k, dim3(B_), dim3(256), 0, stream,
                     table, Wv, bv, Wc, bc, bev, bdist, bfeat, RPR, out);
}